// Round 1
// baseline (127.316 us; speedup 1.0000x reference)
//
#include <hip/hip_runtime.h>
#include <hip/hip_bf16.h>
#include <stdint.h>

// B=16, T=2048, E=1024, H=128
typedef __attribute__((ext_vector_type(8))) short bf16x8;
typedef __attribute__((ext_vector_type(16))) float f32x16;
typedef __attribute__((ext_vector_type(4))) float f32x4;

__device__ __forceinline__ uint32_t cvt_pk_bf16(float a, float b){
  uint32_t r;
  asm volatile("v_cvt_pk_bf16_f32 %0, %1, %2" : "=v"(r) : "v"(a), "v"(b));
  return r;
}
__device__ __forceinline__ void permswap32(uint32_t &a, uint32_t &b){
  asm volatile("v_permlane32_swap_b32 %0, %1" : "+v"(a), "+v"(b));
}
__device__ __forceinline__ unsigned short f2bf(float f){
  uint32_t u = __float_as_uint(f);
  u += 0x7fff + ((u >> 16) & 1);   // RNE
  return (unsigned short)(u >> 16);
}

// ---------------- Kernel 1: W -> Wt bf16 [384][1024]  (rows: 0-127 Q(scaled), 128-255 K, 256-383 V)
__global__ void prep_w(const float* __restrict__ Wk, const float* __restrict__ Wq,
                       const float* __restrict__ Wv, unsigned short* __restrict__ Wt){
  int idx = blockIdx.x * 256 + threadIdx.x;       // 0 .. 393215
  int mat = idx >> 17;
  int r = idx & 131071;                            // e*128 + h
  int h = r & 127;
  int e = r >> 7;
  const float* src = (mat == 0) ? Wq : (mat == 1) ? Wk : Wv;
  float v = src[r];
  if (mat == 0) v *= (1.4426950408889634f * 0.08838834764831845f); // log2e/sqrt(128)
  Wt[(mat * 128 + h) * 1024 + e] = f2bf(v);
}

// ---------------- Kernel 2: fused QKV projection GEMM.  BM=64, BN=384, BK=32.
#define LS 40   // padded LDS stride (elements)
__global__ __launch_bounds__(256, 2) void proj_gemm(
    const float* __restrict__ x, const unsigned short* __restrict__ Wt,
    unsigned short* __restrict__ Qb, unsigned short* __restrict__ Kb,
    unsigned short* __restrict__ Vt){
  __shared__ __align__(16) unsigned short As[64 * LS];
  __shared__ __align__(16) unsigned short Bs[384 * LS];
  const int tid  = threadIdx.x;
  const int lane = tid & 63;
  const int w    = tid >> 6;        // wave 0..3 = column group
  const int lr   = lane & 15;
  const int lk   = lane >> 4;       // 0..3
  const int m0   = blockIdx.x * 64; // token-tile base (flat M=32768)

  f32x4 acc[4][6];
  #pragma unroll
  for (int i = 0; i < 4; ++i)
    #pragma unroll
    for (int jj = 0; jj < 6; ++jj) acc[i][jj] = (f32x4){0.f, 0.f, 0.f, 0.f};

  float4 areg[2];
  bf16x8 breg[6];
  // prefetch ks=0
  #pragma unroll
  for (int i = 0; i < 2; ++i){
    int idx = i * 256 + tid; int row = idx >> 3, kp = idx & 7;
    areg[i] = *(const float4*)(x + (size_t)(m0 + row) * 1024 + kp * 4);
  }
  #pragma unroll
  for (int i = 0; i < 6; ++i){
    int idx = i * 256 + tid; int row = idx >> 2, pp = idx & 3;
    breg[i] = *(const bf16x8*)(Wt + (size_t)row * 1024 + pp * 8);
  }

  for (int ks = 0; ks < 32; ++ks){
    __syncthreads();
    #pragma unroll
    for (int i = 0; i < 2; ++i){
      int idx = i * 256 + tid; int row = idx >> 3, kp = idx & 7;
      uint32_t lo = cvt_pk_bf16(areg[i].x, areg[i].y);
      uint32_t hi = cvt_pk_bf16(areg[i].z, areg[i].w);
      *(uint2*)((char*)As + row * (LS * 2) + kp * 8) = make_uint2(lo, hi);
    }
    #pragma unroll
    for (int i = 0; i < 6; ++i){
      int idx = i * 256 + tid; int row = idx >> 2, pp = idx & 3;
      *(bf16x8*)((char*)Bs + row * (LS * 2) + pp * 16) = breg[i];
    }
    __syncthreads();
    if (ks + 1 < 32){
      int ko = (ks + 1) * 32;
      #pragma unroll
      for (int i = 0; i < 2; ++i){
        int idx = i * 256 + tid; int row = idx >> 3, kp = idx & 7;
        areg[i] = *(const float4*)(x + (size_t)(m0 + row) * 1024 + ko + kp * 4);
      }
      #pragma unroll
      for (int i = 0; i < 6; ++i){
        int idx = i * 256 + tid; int row = idx >> 2, pp = idx & 3;
        breg[i] = *(const bf16x8*)(Wt + (size_t)row * 1024 + ko + pp * 8);
      }
    }
    bf16x8 af[4], bfr[6];
    #pragma unroll
    for (int am = 0; am < 4; ++am)
      af[am] = *(const bf16x8*)((char*)As + (am * 16 + lr) * (LS * 2) + lk * 16);
    #pragma unroll
    for (int bn = 0; bn < 6; ++bn)
      bfr[bn] = *(const bf16x8*)((char*)Bs + (w * 96 + bn * 16 + lr) * (LS * 2) + lk * 16);
    #pragma unroll
    for (int am = 0; am < 4; ++am)
      #pragma unroll
      for (int bn = 0; bn < 6; ++bn)
        acc[am][bn] = __builtin_amdgcn_mfma_f32_16x16x32_bf16(af[am], bfr[bn], acc[am][bn], 0, 0, 0);
  }

  const int b  = m0 >> 11;
  const int t0 = m0 & 2047;
  #pragma unroll
  for (int am = 0; am < 4; ++am){
    #pragma unroll
    for (int bn = 0; bn < 6; ++bn){
      int c0   = w * 96 + bn * 16;
      int mat  = c0 >> 7;
      int hcol = (c0 & 127) + lr;
      int tr   = t0 + am * 16 + lk * 4;    // D: row=(lane>>4)*4+j, col=lane&15
      f32x4 v = acc[am][bn];
      if (mat == 0){
        #pragma unroll
        for (int jj = 0; jj < 4; ++jj)
          Qb[(size_t)(b * 2048 + tr + jj) * 128 + hcol] = f2bf(v[jj]);
      } else if (mat == 1){
        #pragma unroll
        for (int jj = 0; jj < 4; ++jj)
          Kb[(size_t)(b * 2048 + tr + jj) * 128 + hcol] = f2bf(v[jj]);
      } else { // V transposed: Vt[b][h][t], 4 consecutive t -> 8B store
        ushort4 pk;
        pk.x = f2bf(v[0]); pk.y = f2bf(v[1]); pk.z = f2bf(v[2]); pk.w = f2bf(v[3]);
        *(ushort4*)(Vt + (size_t)(b * 128 + hcol) * 2048 + tr) = pk;
      }
    }
  }
}

// ---------------- Kernel 3: causal flash attention, swapped-QK 32x32x16, kv-split-2 + pairing.
__global__ __launch_bounds__(256, 1) void attn(
    const unsigned short* __restrict__ Qb, const unsigned short* __restrict__ Kb,
    const unsigned short* __restrict__ Vt, float* __restrict__ out){
  __shared__ float comb[2][32][132];
  __shared__ float msh[2][32];
  __shared__ float lsh[2][32];

  const int tid   = threadIdx.x;
  const int lane  = tid & 63;
  const int w     = tid >> 6;
  const int pairi = w >> 1;     // 2 pairs per block
  const int half  = w & 1;      // kv parity split
  const int b     = blockIdx.x >> 4;
  const int j     = blockIdx.x & 15;
  const int p     = 2 * j + pairi;     // 0..31
  const int q5    = lane & 31;
  const int hi    = lane >> 5;

  #pragma unroll 1
  for (int ci = 0; ci < 2; ++ci){
    const int c  = (ci == 0) ? p : (63 - p);   // 32-row q-chunk index; balanced pair
    const int r0 = c * 32;

    bf16x8 qf[8];
    const unsigned short* qptr = Qb + (size_t)(b * 2048 + r0 + q5) * 128 + hi * 8;
    #pragma unroll
    for (int f = 0; f < 8; ++f) qf[f] = *(const bf16x8*)(qptr + f * 16);

    f32x16 oacc[4];
    #pragma unroll
    for (int i = 0; i < 4; ++i) oacc[i] = (f32x16)(0.f);
    float m = -1e30f, l = 0.f;

    for (int t = half; t <= c; t += 2){
      const int s0 = t * 32;
      bf16x8 kf[8];
      const unsigned short* kptr = Kb + (size_t)(b * 2048 + s0 + q5) * 128 + hi * 8;
      #pragma unroll
      for (int f = 0; f < 8; ++f) kf[f] = *(const bf16x8*)(kptr + f * 16);
      f32x16 sacc = (f32x16)(0.f);   // S^T[s][q] = sum_h K[s][h] Q[q][h]
      #pragma unroll
      for (int f = 0; f < 8; ++f)
        sacc = __builtin_amdgcn_mfma_f32_32x32x16_bf16(kf[f], qf[f], sacc, 0, 0, 0);
      // V^T frags issued early (latency hides under softmax)
      bf16x8 vf[8];
      #pragma unroll
      for (int ht = 0; ht < 4; ++ht)
        #pragma unroll
        for (int sf = 0; sf < 2; ++sf)
          vf[ht * 2 + sf] = *(const bf16x8*)(Vt + (size_t)(b * 128 + ht * 32 + q5) * 2048 + s0 + sf * 16 + hi * 8);

      float sv[16];
      #pragma unroll
      for (int r = 0; r < 16; ++r) sv[r] = sacc[r];
      if (t == c){   // diagonal tile: mask s>q  (row = (r&3)+8*(r>>2)+4*hi, col q = q5)
        #pragma unroll
        for (int r = 0; r < 16; ++r){
          int srow = (r & 3) + 8 * (r >> 2) + 4 * hi;
          if (srow > q5) sv[r] = -1e30f;
        }
      }
      float pm = sv[0];
      #pragma unroll
      for (int r = 1; r < 16; ++r) pm = fmaxf(pm, sv[r]);
      pm = fmaxf(pm, __shfl_xor(pm, 32));
      if (!__all(pm - m <= 8.0f)){   // defer-max (log2 domain)
        float mn = fmaxf(m, pm);
        float al = exp2f(m - mn);
        #pragma unroll
        for (int i = 0; i < 4; ++i) oacc[i] *= al;
        l *= al;
        m = mn;
      }
      float pv[16]; float ts = 0.f;
      #pragma unroll
      for (int r = 0; r < 16; ++r){ pv[r] = exp2f(sv[r] - m); ts += pv[r]; }
      ts += __shfl_xor(ts, 32);
      l += ts;
      // P^T -> bf16 B-frags: cvt_pk + permlane32_swap (fills both k-halves)
      uint32_t w0 = cvt_pk_bf16(pv[0],  pv[1]);
      uint32_t w2 = cvt_pk_bf16(pv[4],  pv[5]);  permswap32(w0, w2);
      uint32_t w1 = cvt_pk_bf16(pv[2],  pv[3]);
      uint32_t w3 = cvt_pk_bf16(pv[6],  pv[7]);  permswap32(w1, w3);
      uint32_t w4 = cvt_pk_bf16(pv[8],  pv[9]);
      uint32_t w6 = cvt_pk_bf16(pv[12], pv[13]); permswap32(w4, w6);
      uint32_t w5 = cvt_pk_bf16(pv[10], pv[11]);
      uint32_t w7 = cvt_pk_bf16(pv[14], pv[15]); permswap32(w5, w7);
      union { uint32_t u[4]; bf16x8 v; } pf0u, pf1u;
      pf0u.u[0] = w0; pf0u.u[1] = w1; pf0u.u[2] = w2; pf0u.u[3] = w3;
      pf1u.u[0] = w4; pf1u.u[1] = w5; pf1u.u[2] = w6; pf1u.u[3] = w7;
      #pragma unroll
      for (int ht = 0; ht < 4; ++ht){   // O^T[h][q] += V^T · P^T
        oacc[ht] = __builtin_amdgcn_mfma_f32_32x32x16_bf16(vf[ht * 2 + 0], pf0u.v, oacc[ht], 0, 0, 0);
        oacc[ht] = __builtin_amdgcn_mfma_f32_32x32x16_bf16(vf[ht * 2 + 1], pf1u.v, oacc[ht], 0, 0, 0);
      }
    }

    // combine the two kv-halves
    if (half == 1){
      #pragma unroll
      for (int ht = 0; ht < 4; ++ht)
        #pragma unroll
        for (int r = 0; r < 16; ++r){
          int h = ht * 32 + (r & 3) + 8 * (r >> 2) + 4 * hi;
          comb[pairi][q5][h] = oacc[ht][r];
        }
      if (hi == 0){ msh[pairi][q5] = m; lsh[pairi][q5] = l; }
    }
    __syncthreads();
    if (half == 0){
      float m1 = msh[pairi][q5], l1 = lsh[pairi][q5];
      float mn = fmaxf(m, m1);
      float a0 = exp2f(m - mn), a1 = exp2f(m1 - mn);
      float lf = l * a0 + l1 * a1;
      float inv = 1.0f / lf;
      #pragma unroll
      for (int ht = 0; ht < 4; ++ht)
        #pragma unroll
        for (int r = 0; r < 16; ++r){
          int h = ht * 32 + (r & 3) + 8 * (r >> 2) + 4 * hi;
          float o = oacc[ht][r] * a0 + comb[pairi][q5][h] * a1;
          comb[pairi][q5][h] = o * inv;
        }
      float* obase = out + (size_t)(b * 2048 + r0) * 128;
      #pragma unroll 4
      for (int it = 0; it < 32; ++it){
        float2 val = *(const float2*)&comb[pairi][it][lane * 2];
        *(float2*)(obase + it * 128 + lane * 2) = val;
      }
    }
    __syncthreads();
  }
}

extern "C" void kernel_launch(void* const* d_in, const int* in_sizes, int n_in,
                              void* d_out, int out_size, void* d_ws, size_t ws_size,
                              hipStream_t stream){
  const float* x  = (const float*)d_in[0];
  // d_in[1] = mask : causal tril by construction, applied structurally
  const float* Wk = (const float*)d_in[2];
  const float* Wq = (const float*)d_in[3];
  const float* Wv = (const float*)d_in[4];
  char* ws = (char*)d_ws;
  unsigned short* Wt = (unsigned short*)(ws);                    // 768 KB
  unsigned short* Qb = (unsigned short*)(ws + (1ull  << 20));    // 8 MB
  unsigned short* Kb = (unsigned short*)(ws + (9ull  << 20));    // 8 MB
  unsigned short* Vt = (unsigned short*)(ws + (17ull << 20));    // 8 MB
  float* out = (float*)d_out;

  hipLaunchKernelGGL(prep_w,    dim3(1536), dim3(256), 0, stream, Wk, Wq, Wv, Wt);
  hipLaunchKernelGGL(proj_gemm, dim3(512),  dim3(256), 0, stream, x, Wt, Qb, Kb, Vt);
  hipLaunchKernelGGL(attn,      dim3(256),  dim3(256), 0, stream, Qb, Kb, Vt, out);
}